// Round 2
// baseline (446.184 us; speedup 1.0000x reference)
//
#include <hip/hip_runtime.h>

// Graph WaveNet GCN on gfx950 — fused propagate+project pipeline.
// out[n,o,w,l] = b[o] + sum_{blk,c} W[o,blk*32+c] * H_blk[n,c,w,l]
//   H_0 = x,  H_{1+p} = x @ P_p over v,  P = [A0, A0^2, A1, A1^2, A2, A2^2]
//
// Xt row order: m = (b*13 + l)*32 + c  -> 128-row tile = 4 complete channel
// groups, so each block projects its own Y-tile through LDS (Y never hits HBM).
//
// ws layout (bytes):
//   XT   @ 0          : Xt[m][v] bf16, 26624 x 512
//   BT   @ 27262976   : Bt[p][w][v] bf16 (P_p^T), 6 x 512x512
//   ABF  @ 30408704   : A_s bf16 row-major, 3 x 512x512
//   WBF  @ 31981568   : W bf16 [64][224]

typedef unsigned short u16;
typedef unsigned int   u32;
typedef __bf16 bf16x8 __attribute__((ext_vector_type(8)));
typedef float  f32x4  __attribute__((ext_vector_type(4)));
typedef u16    u16x4  __attribute__((ext_vector_type(4)));
typedef u16    u16x8  __attribute__((ext_vector_type(8)));

#define DEVI static __device__ __forceinline__

#define NV   512
#define NL   13
#define SZA  262144L        // 512*512
#define YP   136            // Yt row pitch (u16), 272 B = 17*16 -> 16B aligned rows
#define WP   232            // Ws row pitch (u16), 464 B = 29*16

DEVI u16 f2bf(float f) {
  union { float f; u32 u; } v; v.f = f;
  u32 u = v.u;
  return (u16)((u + 0x7fffu + ((u >> 16) & 1u)) >> 16);  // RNE
}

DEVI void gl2lds16(const void* g, void* l) {
  __builtin_amdgcn_global_load_lds((__attribute__((address_space(1))) void*)g,
                                   (__attribute__((address_space(3))) void*)l, 16, 0, 0);
}

// ---------------------------------------------------------------- prep: supports
__global__ __launch_bounds__(256) void prep_A(const float* __restrict__ A0,
                                              const float* __restrict__ A1,
                                              const float* __restrict__ A2,
                                              u16* __restrict__ BT,
                                              u16* __restrict__ ABF) {
  const int s = blockIdx.z;
  const float* A = (s == 0) ? A0 : ((s == 1) ? A1 : A2);
  u16* abf = ABF + (long)s * SZA;
  u16* bt  = BT + (long)(2 * s) * SZA;
  __shared__ float t[32][33];
  const int v0 = blockIdx.x * 32, w0 = blockIdx.y * 32;
  const int tid = threadIdx.x;
  for (int i = tid; i < 1024; i += 256) {
    const int r = i >> 5, c = i & 31;
    const float val = A[(long)(v0 + r) * 512 + w0 + c];
    t[r][c] = val;
    abf[(long)(v0 + r) * 512 + w0 + c] = f2bf(val);
  }
  __syncthreads();
  for (int i = tid; i < 1024; i += 256) {
    const int r = i >> 5, c = i & 31;
    bt[(long)(w0 + r) * 512 + v0 + c] = f2bf(t[c][r]);
  }
}

// ---------------------------------------------------------------- prep: W -> bf16
__global__ __launch_bounds__(256) void prep_W(const float* __restrict__ W,
                                              u16* __restrict__ WBF) {
  const int i = blockIdx.x * 256 + threadIdx.x;
  WBF[i] = f2bf(W[i]);
}

// ---------------------------------------------------------------- transpose x
// x[b][c][v][l] fp32 -> Xt[(b*13+l)*32+c][v] bf16. One block per (b,c).
__global__ __launch_bounds__(256) void transpose_x(const float* __restrict__ x,
                                                   u16* __restrict__ XT) {
  __shared__ __align__(16) float tile[NV * NL];  // 26.6 KB
  const int bc = blockIdx.x;
  const int b = bc >> 5, c = bc & 31;
  const float4* src4 = (const float4*)(x + (long)bc * (NV * NL));
  float4* t4 = (float4*)tile;
  for (int i = threadIdx.x; i < (NV * NL) / 4; i += 256) t4[i] = src4[i];
  __syncthreads();
  for (int j = threadIdx.x; j < NL * 256; j += 256) {
    const int l = j >> 8, v = (j & 255) * 2;   // two adjacent v per thread
    const long row = (long)(b * 13 + l) * 32 + c;
    const u32 lo = f2bf(tile[v * NL + l]);
    const u32 hi = f2bf(tile[(v + 1) * NL + l]);
    *(u32*)&XT[row * 512 + v] = lo | (hi << 16);
  }
}

// ---------------------------------------------------------------- small NT GEMM (P^2)
__global__ __launch_bounds__(256) void gemm512(const u16* __restrict__ Ag,
                                               const u16* __restrict__ Bg,
                                               u16* __restrict__ Cg,
                                               long aZ, long bZ, long cZ) {
  __shared__ __align__(16) u16 As[128 * 32];
  __shared__ __align__(16) u16 Bs[128 * 32];
  const int p = blockIdx.z;
  const u16* A = Ag + (long)p * aZ;
  const u16* B = Bg + (long)p * bZ;
  u16*       C = Cg + (long)p * cZ;
  const int m0 = blockIdx.y * 128, n0 = blockIdx.x * 128;
  const int tid = threadIdx.x;
  const int lane = tid & 63, wid = tid >> 6;
  const int wm = wid >> 1, wn = wid & 1;
  const int lr = lane & 15, lq = lane >> 4;
  const int srow = lane >> 2, skq = lane & 3;

  f32x4 acc[4][4] = {};

  for (int kt = 0; kt < 16; ++kt) {
    const int k0 = kt * 32;
    __syncthreads();
#pragma unroll
    for (int j = 0; j < 2; ++j) {
      const int rb = wid * 32 + j * 16;
      gl2lds16(A + (long)(m0 + rb + srow) * 512 + (k0 + skq * 8), &As[rb * 32]);
      gl2lds16(B + (long)(n0 + rb + srow) * 512 + (k0 + skq * 8), &Bs[rb * 32]);
    }
    __syncthreads();
    bf16x8 af[4], bv[4];
#pragma unroll
    for (int t = 0; t < 4; ++t) {
      af[t] = *(const bf16x8*)&As[(wm * 64 + t * 16 + lr) * 32 + lq * 8];
      bv[t] = *(const bf16x8*)&Bs[(wn * 64 + t * 16 + lr) * 32 + lq * 8];
    }
#pragma unroll
    for (int i = 0; i < 4; ++i)
#pragma unroll
      for (int j = 0; j < 4; ++j)
        acc[i][j] = __builtin_amdgcn_mfma_f32_16x16x32_bf16(af[i], bv[j], acc[i][j], 0, 0, 0);
  }
#pragma unroll
  for (int i = 0; i < 4; ++i) {
    const int mr = m0 + wm * 64 + i * 16 + lq * 4;
#pragma unroll
    for (int j = 0; j < 4; ++j) {
      const int nc = n0 + wn * 64 + j * 16 + lr;
#pragma unroll
      for (int r = 0; r < 4; ++r)
        C[(long)(mr + r) * 512 + nc] = f2bf(acc[i][j][r]);
    }
  }
}

// ---------------------------------------------------------------- fused GCN
// One block: 128 m-rows (4 channel groups = 4 (b,l) pairs) x 128 w.
// 512 threads / 8 waves. Per pass (3 passes, 2 p each):
//   K-loop (2-phase, dbuf) computes Yt_acc[w][m] for both p's; each Y-tile is
//   written bf16 to LDS (chunk-swizzled) and projected with W-block MFMAs into
//   per-wave out accumulators. Block 0 (x) is loaded+transposed into the same
//   LDS tile and projected first. Y never touches HBM.
__global__ __launch_bounds__(512) void fused_gcn(const u16* __restrict__ XT,
                                                 const u16* __restrict__ BT,
                                                 const u16* __restrict__ WBF,
                                                 const float* __restrict__ bias,
                                                 float* __restrict__ out) {
  __shared__ __align__(16) u16 As[2][128 * 32];
  __shared__ __align__(16) u16 Bs0[2][128 * 32];
  __shared__ __align__(16) u16 Bs1[2][128 * 32];
  __shared__ __align__(16) u16 Yt[128 * YP];   // [w][m-swizzled], 34816 B
  __shared__ __align__(16) u16 Ws[64 * WP];    // W bf16, pitched   29696 B

  // grid decode: XCD k = P%8 exclusively owns b in [8k,8k+8)
  // (104 = 8*13 row-groups per XCD -> 26 m-panels * 4 w-tiles, exact).
  const int P = blockIdx.x;
  const int xcd = P & 7, inner = P >> 3;
  const int ym = xcd * 26 + (inner >> 2);   // m-panel 0..207
  const int m0 = ym * 128;
  const int w0 = (inner & 3) * 128;

  const int tid  = threadIdx.x;
  const int lane = tid & 63, wid = tid >> 6;
  const int lr = lane & 15, lq = lane >> 4;
  const int wv = wid & 1, wm = wid >> 1;      // main gemm: w-half, m-quarter
  const int g  = wid >> 1, h  = wid & 1;      // projection: channel group, w-half
  const int srow = tid >> 2, skq = tid & 3;   // staging: row, 16B chunk
  const int scol = (skq ^ ((srow >> 1) & 3)) * 8;  // pre-swizzled global chunk
  const int ldsb = wid * 512;                 // wave-uniform stage base (u16)
  const int co = (lq ^ ((lr >> 1) & 3)) * 8;  // swizzled read chunk offset

  // ---- W -> LDS (pitched)
  for (int i = tid; i < 64 * 56; i += 512) {
    const int row = i / 56, c4 = (i - row * 56) * 4;
    *(u16x4*)&Ws[row * WP + c4] = *(const u16x4*)&WBF[row * 224 + c4];
  }
  // ---- X tile -> Yt (transposed + chunk-swizzled): Yt[w][m] = Xt[m0+m][w0+w]
  for (int i = tid; i < 2048; i += 512) {
    const int mrow = i >> 4, c8 = (i & 15) * 8;
    const u16x8 d = *(const u16x8*)&XT[(long)(m0 + mrow) * 512 + w0 + c8];
#pragma unroll
    for (int z = 0; z < 8; ++z) {
      const int w = c8 + z;
      Yt[w * YP + ((((mrow >> 3) ^ ((w >> 3) & 3)) << 3) | (mrow & 7))] = d[z];
    }
  }
  __syncthreads();

  f32x4 oacc[4][4] = {};   // [o-frag][w-frag] for (g,h)

#define STAGE(Bp0_, Bp1_, kk, bb) do {                                         \
    const int kc_ = (kk) * 32 + scol;                                          \
    gl2lds16(XT     + (long)(m0 + srow) * 512 + kc_, &As [bb][ldsb]);          \
    gl2lds16((Bp0_) + (long)(w0 + srow) * 512 + kc_, &Bs0[bb][ldsb]);          \
    gl2lds16((Bp1_) + (long)(w0 + srow) * 512 + kc_, &Bs1[bb][ldsb]);          \
  } while (0)

#define PROJ(blk) do {                                                         \
    bf16x8 paf_[4], pbv_[4];                                                   \
    _Pragma("unroll")                                                          \
    for (int oi = 0; oi < 4; ++oi)                                             \
      paf_[oi] = *(const bf16x8*)&Ws[(oi * 16 + lr) * WP + (blk) * 32 + lq * 8]; \
    _Pragma("unroll")                                                          \
    for (int wj = 0; wj < 4; ++wj) {                                           \
      const int w_ = h * 64 + wj * 16 + lr;                                    \
      pbv_[wj] = *(const bf16x8*)&Yt[w_ * YP + (((g * 4 + lq) ^ ((w_ >> 3) & 3)) << 3)]; \
    }                                                                          \
    _Pragma("unroll")                                                          \
    for (int oi = 0; oi < 4; ++oi)                                             \
      _Pragma("unroll")                                                        \
      for (int wj = 0; wj < 4; ++wj)                                           \
        oacc[oi][wj] = __builtin_amdgcn_mfma_f32_16x16x32_bf16(paf_[oi], pbv_[wj], oacc[oi][wj], 0, 0, 0); \
  } while (0)

#define WRB(ac) do {                                                           \
    _Pragma("unroll")                                                          \
    for (int i = 0; i < 4; ++i)                                                \
      _Pragma("unroll")                                                        \
      for (int j = 0; j < 2; ++j)                                              \
        _Pragma("unroll")                                                      \
        for (int r = 0; r < 4; ++r) {                                          \
          const int w_ = wv * 64 + i * 16 + lq * 4 + r;                        \
          const int m_ = wm * 32 + j * 16 + lr;                                \
          Yt[w_ * YP + ((((m_ >> 3) ^ ((w_ >> 3) & 3)) << 3) | (m_ & 7))] = f2bf(ac[i][j][r]); \
        }                                                                      \
  } while (0)

  for (int pass = 0; pass < 3; ++pass) {
    const u16* Bp0 = BT + (long)(2 * pass) * SZA;
    const u16* Bp1 = BT + (long)(2 * pass + 1) * SZA;
    STAGE(Bp0, Bp1, 0, 0);          // pre-stage kt=0 (overlaps projection)
    PROJ(2 * pass);                 // pass0: blk0 on X; else blk 2*pass on Y[2*pass-1]
    __syncthreads();                // stage complete + Yt proj reads done
    f32x4 accA[4][2] = {}, accB[4][2] = {};
    for (int kt = 0; kt < 16; ++kt) {
      const int buf = kt & 1;
      if (kt < 15) STAGE(Bp0, Bp1, kt + 1, buf ^ 1);
      bf16x8 a0[4], a1[4], bv[2];
#pragma unroll
      for (int i = 0; i < 4; ++i) {
        a0[i] = *(const bf16x8*)&Bs0[buf][(wv * 64 + i * 16 + lr) * 32 + co];
        a1[i] = *(const bf16x8*)&Bs1[buf][(wv * 64 + i * 16 + lr) * 32 + co];
      }
#pragma unroll
      for (int j = 0; j < 2; ++j)
        bv[j] = *(const bf16x8*)&As[buf][(wm * 32 + j * 16 + lr) * 32 + co];
#pragma unroll
      for (int i = 0; i < 4; ++i)
#pragma unroll
        for (int j = 0; j < 2; ++j) {
          accA[i][j] = __builtin_amdgcn_mfma_f32_16x16x32_bf16(a0[i], bv[j], accA[i][j], 0, 0, 0);
          accB[i][j] = __builtin_amdgcn_mfma_f32_16x16x32_bf16(a1[i], bv[j], accB[i][j], 0, 0, 0);
        }
      __syncthreads();
    }
    WRB(accA);
    __syncthreads();
    PROJ(2 * pass + 1);             // Y[2*pass]
    __syncthreads();
    WRB(accB);
    __syncthreads();
  }
  PROJ(6);                          // Y[5]

  // epilogue: out[((b*64+o)*512+w)*13 + l]
  const int bl = ym * 4 + g;
  const int b  = bl / 13, l = bl - b * 13;
  float* outb = out + (long)b * (64L * 512 * 13) + l;
#pragma unroll
  for (int oi = 0; oi < 4; ++oi) {
    const f32x4 bi = *(const f32x4*)&bias[oi * 16 + lq * 4];
#pragma unroll
    for (int wj = 0; wj < 4; ++wj) {
      const int w = w0 + h * 64 + wj * 16 + lr;
      const long base = ((long)(oi * 16 + lq * 4) * 512 + w) * 13;
#pragma unroll
      for (int r = 0; r < 4; ++r)
        outb[base + (long)r * (512 * 13)] = oacc[oi][wj][r] + bi[r];
    }
  }
#undef STAGE
#undef PROJ
#undef WRB
}

extern "C" void kernel_launch(void* const* d_in, const int* in_sizes, int n_in,
                              void* d_out, int out_size, void* d_ws, size_t ws_size,
                              hipStream_t stream) {
  const float* x  = (const float*)d_in[0];
  const float* s0 = (const float*)d_in[1];
  const float* s1 = (const float*)d_in[2];
  const float* s2 = (const float*)d_in[3];
  const float* W  = (const float*)d_in[4];
  const float* b  = (const float*)d_in[5];
  float* out = (float*)d_out;

  char* ws = (char*)d_ws;
  u16* XT  = (u16*)(ws);
  u16* BT  = (u16*)(ws + 27262976L);
  u16* ABF = (u16*)(ws + 30408704L);
  u16* WBF = (u16*)(ws + 31981568L);

  prep_A<<<dim3(16, 16, 3), 256, 0, stream>>>(s0, s1, s2, BT, ABF);
  prep_W<<<dim3(56), 256, 0, stream>>>(W, WBF);
  // Bt[2s+1] = (A_s^2)^T = Bt[2s] (NT) ABF[s]
  gemm512<<<dim3(4, 4, 3), 256, 0, stream>>>(BT, ABF, BT + SZA,
                                             2L * SZA, 1L * SZA, 2L * SZA);
  transpose_x<<<dim3(64 * 32), 256, 0, stream>>>(x, XT);
  fused_gcn<<<dim3(832), 512, 0, stream>>>(XT, BT, WBF, b, out);
}

// Round 3
// 419.801 us; speedup vs baseline: 1.0628x; 1.0628x over previous
//
#include <hip/hip_runtime.h>

// Graph WaveNet GCN on gfx950 — fused propagate+project, counted-vmcnt pipeline.
// out[n,o,w,l] = b[o] + sum_{blk,c} W[o,blk*32+c] * H_blk[n,c,w,l]
//   H_0 = x,  H_{1+p} = x @ P_p over v,  P = [A0, A0^2, A1, A1^2, A2, A2^2]
//
// Xt row order: m = (b*13 + l)*32 + c  -> 128-row tile = 4 complete channel
// groups, so each block projects its own Y-tile through LDS (Y never hits HBM).
//
// K-loop schedule (T3+T4): triple-buffered staging, stage kt+2 each kt,
// s_waitcnt vmcnt(3) (never 0 mid-loop), ONE s_barrier per kt.
//
// ws layout (bytes):
//   XT   @ 0          : Xt[m][v] bf16, 26624 x 512
//   BT   @ 27262976   : Bt[p][w][v] bf16 (P_p^T), 6 x 512x512
//   ABF  @ 30408704   : A_s bf16 row-major, 3 x 512x512
//   WBF  @ 31981568   : W bf16 [64][224]

typedef unsigned short u16;
typedef unsigned int   u32;
typedef __bf16 bf16x8 __attribute__((ext_vector_type(8)));
typedef float  f32x4  __attribute__((ext_vector_type(4)));
typedef u16    u16x4  __attribute__((ext_vector_type(4)));
typedef u16    u16x8  __attribute__((ext_vector_type(8)));

#define DEVI static __device__ __forceinline__

#define NV   512
#define NL   13
#define SZA  262144L        // 512*512
#define YP   136            // Yt row pitch (u16), 272 B -> rows start 4 banks apart
#define WP   232            // Ws row pitch (u16), 464 B

#define VMCNT(n) asm volatile("s_waitcnt vmcnt(" #n ")" ::: "memory")
#define LGKM0    asm volatile("s_waitcnt lgkmcnt(0)" ::: "memory")
#define CFENCE   asm volatile("" ::: "memory")
#define BAR()    __builtin_amdgcn_s_barrier()

DEVI u16 f2bf(float f) {
  union { float f; u32 u; } v; v.f = f;
  u32 u = v.u;
  return (u16)((u + 0x7fffu + ((u >> 16) & 1u)) >> 16);  // RNE
}

DEVI void gl2lds16(const void* g, void* l) {
  __builtin_amdgcn_global_load_lds((__attribute__((address_space(1))) void*)g,
                                   (__attribute__((address_space(3))) void*)l, 16, 0, 0);
}

// ---------------------------------------------------------------- prep: supports
__global__ __launch_bounds__(256) void prep_A(const float* __restrict__ A0,
                                              const float* __restrict__ A1,
                                              const float* __restrict__ A2,
                                              u16* __restrict__ BT,
                                              u16* __restrict__ ABF) {
  const int s = blockIdx.z;
  const float* A = (s == 0) ? A0 : ((s == 1) ? A1 : A2);
  u16* abf = ABF + (long)s * SZA;
  u16* bt  = BT + (long)(2 * s) * SZA;
  __shared__ float t[32][33];
  const int v0 = blockIdx.x * 32, w0 = blockIdx.y * 32;
  const int tid = threadIdx.x;
  for (int i = tid; i < 1024; i += 256) {
    const int r = i >> 5, c = i & 31;
    const float val = A[(long)(v0 + r) * 512 + w0 + c];
    t[r][c] = val;
    abf[(long)(v0 + r) * 512 + w0 + c] = f2bf(val);
  }
  __syncthreads();
  for (int i = tid; i < 1024; i += 256) {
    const int r = i >> 5, c = i & 31;
    bt[(long)(w0 + r) * 512 + v0 + c] = f2bf(t[c][r]);
  }
}

// ---------------------------------------------------------------- prep: W -> bf16
__global__ __launch_bounds__(256) void prep_W(const float* __restrict__ W,
                                              u16* __restrict__ WBF) {
  const int i = blockIdx.x * 256 + threadIdx.x;
  WBF[i] = f2bf(W[i]);
}

// ---------------------------------------------------------------- transpose x
// x[b][c][v][l] fp32 -> Xt[(b*13+l)*32+c][v] bf16. One block per (b,c).
__global__ __launch_bounds__(256) void transpose_x(const float* __restrict__ x,
                                                   u16* __restrict__ XT) {
  __shared__ __align__(16) float tile[NV * NL];  // 26.6 KB
  const int bc = blockIdx.x;
  const int b = bc >> 5, c = bc & 31;
  const float4* src4 = (const float4*)(x + (long)bc * (NV * NL));
  float4* t4 = (float4*)tile;
  for (int i = threadIdx.x; i < (NV * NL) / 4; i += 256) t4[i] = src4[i];
  __syncthreads();
  for (int j = threadIdx.x; j < NL * 256; j += 256) {
    const int l = j >> 8, v = (j & 255) * 2;   // two adjacent v per thread
    const long row = (long)(b * 13 + l) * 32 + c;
    const u32 lo = f2bf(tile[v * NL + l]);
    const u32 hi = f2bf(tile[(v + 1) * NL + l]);
    *(u32*)&XT[row * 512 + v] = lo | (hi << 16);
  }
}

// ---------------------------------------------------------------- small NT GEMM (P^2)
__global__ __launch_bounds__(256) void gemm512(const u16* __restrict__ Ag,
                                               const u16* __restrict__ Bg,
                                               u16* __restrict__ Cg,
                                               long aZ, long bZ, long cZ) {
  __shared__ __align__(16) u16 As[128 * 32];
  __shared__ __align__(16) u16 Bs[128 * 32];
  const int p = blockIdx.z;
  const u16* A = Ag + (long)p * aZ;
  const u16* B = Bg + (long)p * bZ;
  u16*       C = Cg + (long)p * cZ;
  const int m0 = blockIdx.y * 128, n0 = blockIdx.x * 128;
  const int tid = threadIdx.x;
  const int lane = tid & 63, wid = tid >> 6;
  const int wm = wid >> 1, wn = wid & 1;
  const int lr = lane & 15, lq = lane >> 4;
  const int srow = lane >> 2, skq = lane & 3;

  f32x4 acc[4][4] = {};

  for (int kt = 0; kt < 16; ++kt) {
    const int k0 = kt * 32;
    __syncthreads();
#pragma unroll
    for (int j = 0; j < 2; ++j) {
      const int rb = wid * 32 + j * 16;
      gl2lds16(A + (long)(m0 + rb + srow) * 512 + (k0 + skq * 8), &As[rb * 32]);
      gl2lds16(B + (long)(n0 + rb + srow) * 512 + (k0 + skq * 8), &Bs[rb * 32]);
    }
    __syncthreads();
    bf16x8 af[4], bv[4];
#pragma unroll
    for (int t = 0; t < 4; ++t) {
      af[t] = *(const bf16x8*)&As[(wm * 64 + t * 16 + lr) * 32 + lq * 8];
      bv[t] = *(const bf16x8*)&Bs[(wn * 64 + t * 16 + lr) * 32 + lq * 8];
    }
#pragma unroll
    for (int i = 0; i < 4; ++i)
#pragma unroll
      for (int j = 0; j < 4; ++j)
        acc[i][j] = __builtin_amdgcn_mfma_f32_16x16x32_bf16(af[i], bv[j], acc[i][j], 0, 0, 0);
  }
#pragma unroll
  for (int i = 0; i < 4; ++i) {
    const int mr = m0 + wm * 64 + i * 16 + lq * 4;
#pragma unroll
    for (int j = 0; j < 4; ++j) {
      const int nc = n0 + wn * 64 + j * 16 + lr;
#pragma unroll
      for (int r = 0; r < 4; ++r)
        C[(long)(mr + r) * 512 + nc] = f2bf(acc[i][j][r]);
    }
  }
}

// ---------------------------------------------------------------- fused GCN
// One block: 128 m-rows (4 channel groups) x 128 w. 512 threads / 8 waves.
// Main-GEMM wave tile: 32w x 64m (ww=wid&3, wm2=wid>>2): 8 ds_read_b128 per
// 16 MFMA. K-loop: triple-buffer, stage kt+2, vmcnt(3), one barrier per kt.
__global__ __launch_bounds__(512) void fused_gcn(const u16* __restrict__ XT,
                                                 const u16* __restrict__ BT,
                                                 const u16* __restrict__ WBF,
                                                 const float* __restrict__ bias,
                                                 float* __restrict__ out) {
  __shared__ __align__(16) u16 As [3][128 * 32];
  __shared__ __align__(16) u16 Bs0[3][128 * 32];
  __shared__ __align__(16) u16 Bs1[3][128 * 32];
  __shared__ __align__(16) u16 Yt[128 * YP];   // 34816 B
  __shared__ __align__(16) u16 Ws[64 * WP];    // 29696 B  (total LDS 138240)

  // grid decode: XCD k = P%8 exclusively owns b in [8k,8k+8)
  const int P = blockIdx.x;
  const int xcd = P & 7, inner = P >> 3;
  const int ym = xcd * 26 + (inner >> 2);   // m-panel 0..207
  const int m0 = ym * 128;
  const int w0 = (inner & 3) * 128;

  const int tid  = threadIdx.x;
  const int lane = tid & 63, wid = tid >> 6;
  const int lr = lane & 15, lq = lane >> 4;
  const int ww = wid & 3, wm2 = wid >> 2;     // main gemm: w-quarter, m-half
  const int g  = wid >> 1, h  = wid & 1;      // projection: channel group, w-half
  const int srow = tid >> 2, skq = tid & 3;   // staging: row, 16B chunk
  const int scol = (skq ^ ((srow >> 1) & 3)) * 8;  // pre-swizzled global chunk
  const int ldsb = wid * 512;                 // wave-uniform stage base (u16)
  const int co = (lq ^ ((lr >> 1) & 3)) * 8;  // swizzled read chunk offset

  // ---- W -> LDS (pitched)
  for (int i = tid; i < 64 * 56; i += 512) {
    const int row = i / 56, c4 = (i - row * 56) * 4;
    *(u16x4*)&Ws[row * WP + c4] = *(const u16x4*)&WBF[row * 224 + c4];
  }
  // ---- X tile -> Yt (transposed + chunk-swizzled): Yt[w][m] = Xt[m0+m][w0+w]
  for (int i = tid; i < 2048; i += 512) {
    const int mrow = i >> 4, c8 = (i & 15) * 8;
    const u16x8 d = *(const u16x8*)&XT[(long)(m0 + mrow) * 512 + w0 + c8];
#pragma unroll
    for (int z = 0; z < 8; ++z) {
      const int w = c8 + z;
      Yt[w * YP + ((((mrow >> 3) ^ ((w >> 3) & 3)) << 3) | (mrow & 7))] = d[z];
    }
  }
  __syncthreads();   // full drain once: clean vmcnt slate before pass 0

  f32x4 oacc[4][4] = {};   // [o-frag][w-frag] for (g,h)

#define STAGE(Bp0_, Bp1_, kk, bb) do {                                         \
    const int kc_ = (kk) * 32 + scol;                                          \
    gl2lds16(XT     + (long)(m0 + srow) * 512 + kc_, &As [bb][ldsb]);          \
    gl2lds16((Bp0_) + (long)(w0 + srow) * 512 + kc_, &Bs0[bb][ldsb]);          \
    gl2lds16((Bp1_) + (long)(w0 + srow) * 512 + kc_, &Bs1[bb][ldsb]);          \
  } while (0)

#define PROJ(blk) do {                                                         \
    bf16x8 paf_[4], pbv_[4];                                                   \
    _Pragma("unroll")                                                          \
    for (int oi = 0; oi < 4; ++oi)                                             \
      paf_[oi] = *(const bf16x8*)&Ws[(oi * 16 + lr) * WP + (blk) * 32 + lq * 8]; \
    _Pragma("unroll")                                                          \
    for (int wj = 0; wj < 4; ++wj) {                                           \
      const int w_ = h * 64 + wj * 16 + lr;                                    \
      pbv_[wj] = *(const bf16x8*)&Yt[w_ * YP + (((g * 4 + lq) ^ ((w_ >> 3) & 3)) << 3)]; \
    }                                                                          \
    _Pragma("unroll")                                                          \
    for (int oi = 0; oi < 4; ++oi)                                             \
      _Pragma("unroll")                                                        \
      for (int wj = 0; wj < 4; ++wj)                                           \
        oacc[oi][wj] = __builtin_amdgcn_mfma_f32_16x16x32_bf16(paf_[oi], pbv_[wj], oacc[oi][wj], 0, 0, 0); \
  } while (0)

#define WRB(ac) do {                                                           \
    _Pragma("unroll")                                                          \
    for (int i = 0; i < 2; ++i)                                                \
      _Pragma("unroll")                                                        \
      for (int j = 0; j < 4; ++j)                                              \
        _Pragma("unroll")                                                      \
        for (int r = 0; r < 4; ++r) {                                          \
          const int w_ = ww * 32 + i * 16 + lq * 4 + r;                        \
          const int m_ = wm2 * 64 + j * 16 + lr;                               \
          Yt[w_ * YP + ((((m_ >> 3) ^ ((w_ >> 3) & 3)) << 3) | (m_ & 7))] = f2bf(ac[i][j][r]); \
        }                                                                      \
  } while (0)

  for (int pass = 0; pass < 3; ++pass) {
    const u16* Bp0 = BT + (long)(2 * pass) * SZA;
    const u16* Bp1 = BT + (long)(2 * pass + 1) * SZA;
    STAGE(Bp0, Bp1, 0, 0);          // prefetch kt=0  (3 loads in flight)
    STAGE(Bp0, Bp1, 1, 1);          // prefetch kt=1  (6 in flight)
    PROJ(2 * pass);                 // LDS-only: overlaps staging latency
    f32x4 accA[2][4] = {}, accB[2][4] = {};
#pragma unroll
    for (int kt = 0; kt < 16; ++kt) {
      if (kt == 15) { VMCNT(0); } else { VMCNT(3); }   // wait oldest trio only
      BAR();
      CFENCE;
      if (kt < 14) STAGE(Bp0, Bp1, kt + 2, (kt + 2) % 3);
      const int buf = kt % 3;
      bf16x8 a0[2], a1[2], bv[4];
#pragma unroll
      for (int i = 0; i < 2; ++i) {
        a0[i] = *(const bf16x8*)&Bs0[buf][(ww * 32 + i * 16 + lr) * 32 + co];
        a1[i] = *(const bf16x8*)&Bs1[buf][(ww * 32 + i * 16 + lr) * 32 + co];
      }
#pragma unroll
      for (int j = 0; j < 4; ++j)
        bv[j] = *(const bf16x8*)&As[buf][(wm2 * 64 + j * 16 + lr) * 32 + co];
      LGKM0;                       // reads landed before next barrier
#pragma unroll
      for (int i = 0; i < 2; ++i)
#pragma unroll
        for (int j = 0; j < 4; ++j) {
          accA[i][j] = __builtin_amdgcn_mfma_f32_16x16x32_bf16(a0[i], bv[j], accA[i][j], 0, 0, 0);
          accB[i][j] = __builtin_amdgcn_mfma_f32_16x16x32_bf16(a1[i], bv[j], accB[i][j], 0, 0, 0);
        }
    }
    WRB(accA);  LGKM0; BAR(); CFENCE;
    PROJ(2 * pass + 1);  LGKM0; BAR(); CFENCE;
    WRB(accB);  LGKM0; BAR(); CFENCE;
  }
  PROJ(6);

  // epilogue: out[((b*64+o)*512+w)*13 + l]
  const int bl = ym * 4 + g;
  const int b  = bl / 13, l = bl - b * 13;
  float* outb = out + (long)b * (64L * 512 * 13) + l;
#pragma unroll
  for (int oi = 0; oi < 4; ++oi) {
    const f32x4 bi = *(const f32x4*)&bias[oi * 16 + lq * 4];
#pragma unroll
    for (int wj = 0; wj < 4; ++wj) {
      const int w = w0 + h * 64 + wj * 16 + lr;
      const long base = ((long)(oi * 16 + lq * 4) * 512 + w) * 13;
#pragma unroll
      for (int r = 0; r < 4; ++r)
        outb[base + (long)r * (512 * 13)] = oacc[oi][wj][r] + bi[r];
    }
  }
#undef STAGE
#undef PROJ
#undef WRB
}

extern "C" void kernel_launch(void* const* d_in, const int* in_sizes, int n_in,
                              void* d_out, int out_size, void* d_ws, size_t ws_size,
                              hipStream_t stream) {
  const float* x  = (const float*)d_in[0];
  const float* s0 = (const float*)d_in[1];
  const float* s1 = (const float*)d_in[2];
  const float* s2 = (const float*)d_in[3];
  const float* W  = (const float*)d_in[4];
  const float* b  = (const float*)d_in[5];
  float* out = (float*)d_out;

  char* ws = (char*)d_ws;
  u16* XT  = (u16*)(ws);
  u16* BT  = (u16*)(ws + 27262976L);
  u16* ABF = (u16*)(ws + 30408704L);
  u16* WBF = (u16*)(ws + 31981568L);

  prep_A<<<dim3(16, 16, 3), 256, 0, stream>>>(s0, s1, s2, BT, ABF);
  prep_W<<<dim3(56), 256, 0, stream>>>(W, WBF);
  // Bt[2s+1] = (A_s^2)^T = Bt[2s] (NT) ABF[s]
  gemm512<<<dim3(4, 4, 3), 256, 0, stream>>>(BT, ABF, BT + SZA,
                                             2L * SZA, 1L * SZA, 2L * SZA);
  transpose_x<<<dim3(64 * 32), 256, 0, stream>>>(x, XT);
  fused_gcn<<<dim3(832), 512, 0, stream>>>(XT, BT, WBF, b, out);
}